// Round 2
// baseline (762.534 us; speedup 1.0000x reference)
//
#include <hip/hip_runtime.h>
#include <hip/hip_bf16.h>
#include <math.h>

// Problem constants (B, T, D, H, L) = (8, 512, 128, 128, 2). All fp32 I/O.
#define BB 8
#define TT 512
#define DD 128
#define HH 128
#define NROW 8                       // rows of X per projection block
#define BT_ (BB * TT)                // 4096
static const size_t BTH = (size_t)BT_ * HH;  // 524288

struct ProjArgs {
  const float* W[6];  // each already offset to current layer, (H, D)
  const float* b[6];  // each already offset to current layer, (H)
};

// ---------------------------------------------------------------------------
// Projection kernel: act[p][row][h] = act_p( sum_d X[row][d] * W_p[h][d] + b_p[h] )
// p: 0=q(raw) 1=k(*1/sqrt(H)) 2=v(raw) 3=i(exp) 4=f(sigmoid) 5=o(sigmoid)
// grid: (BT_/NROW, 6), block: 256. Thread = one h x 4 rows.
// ---------------------------------------------------------------------------
__global__ __launch_bounds__(256)
void proj_kernel(const float* __restrict__ X, ProjArgs args,
                 float* __restrict__ act) {
  __shared__ float xs[NROW][DD];
  const int p = blockIdx.y;
  const int row0 = blockIdx.x * NROW;
  const int tid = threadIdx.x;
  {
    // NROW*DD = 1024 floats = 256 float4s, one per thread
    const float4* x4 = (const float4*)(X + (size_t)row0 * DD);
    float4* s4 = (float4*)&xs[0][0];
    s4[tid] = x4[tid];
  }
  __syncthreads();

  const int h = tid & 127;
  const int rg = tid >> 7;  // 0..1 -> rows rg*4 + 0..3
  const float4* w4 = (const float4*)(args.W[p] + (size_t)h * DD);
  const float bias = args.b[p][h];

  const float* x0 = &xs[rg * 4 + 0][0];
  const float* x1 = &xs[rg * 4 + 1][0];
  const float* x2 = &xs[rg * 4 + 2][0];
  const float* x3 = &xs[rg * 4 + 3][0];

  float a0 = 0.f, a1 = 0.f, a2 = 0.f, a3 = 0.f;
#pragma unroll
  for (int qq = 0; qq < DD / 4; ++qq) {
    float4 w = w4[qq];
    const int c = 4 * qq;
    a0 = fmaf(x0[c], w.x, fmaf(x0[c+1], w.y, fmaf(x0[c+2], w.z, fmaf(x0[c+3], w.w, a0))));
    a1 = fmaf(x1[c], w.x, fmaf(x1[c+1], w.y, fmaf(x1[c+2], w.z, fmaf(x1[c+3], w.w, a1))));
    a2 = fmaf(x2[c], w.x, fmaf(x2[c+1], w.y, fmaf(x2[c+2], w.z, fmaf(x2[c+3], w.w, a2))));
    a3 = fmaf(x3[c], w.x, fmaf(x3[c+1], w.y, fmaf(x3[c+2], w.z, fmaf(x3[c+3], w.w, a3))));
  }

  float accs[4] = {a0, a1, a2, a3};
#pragma unroll
  for (int j = 0; j < 4; ++j) {
    float a = accs[j] + bias;
    float o;
    if (p == 1)      o = a * 0.088388347648318447f;  // 1/sqrt(128), bias first
    else if (p == 3) o = expf(a);
    else if (p >= 4) o = 1.0f / (1.0f + expf(-a));
    else             o = a;
    act[(size_t)p * BTH + (size_t)(row0 + rg * 4 + j) * HH + h] = o;
  }
}

// ---------------------------------------------------------------------------
// Scan kernel: sequential over T. One wave per block. Block = (batch b,
// 8-row slice of C). Lane layout: row = slice*8 + (lane&7),
// cols = (lane>>3)*16 .. +16 (16 C elements in registers).
// n (length-128) recurrence + denom computed redundantly per block:
// lane owns n[lane], n[lane+64]. h_t uses OLD C and OLD n (per reference).
// ---------------------------------------------------------------------------
struct Step {
  float q[16], k[16];
  float fr, ir, vr, og;                              // row scalars
  float qn0, qn1, kn0, kn1, fn0, fn1, gn0, gn1;      // n-lane values
};

__global__ __launch_bounds__(64)
void scan_kernel(const float* __restrict__ act, float* __restrict__ hout) {
  const int lane = threadIdx.x;
  const int b = blockIdx.x >> 4;   // 16 slices per batch
  const int sl = blockIdx.x & 15;
  const int irow = sl * 8 + (lane & 7);
  const int g = lane >> 3;
  const size_t boff = (size_t)b * TT * HH;
  const float* qp  = act + boff;
  const float* kp  = act + BTH + boff;
  const float* vp  = act + 2 * BTH + boff;
  const float* ipg = act + 3 * BTH + boff;
  const float* fpg = act + 4 * BTH + boff;
  const float* opg = act + 5 * BTH + boff;

  float C[16];
#pragma unroll
  for (int c = 0; c < 16; ++c) C[c] = 0.f;
  float n0 = 0.f, n1 = 0.f;

  auto load_step = [&](int t, Step& S) {
    const int base = t * HH;
    const float4* q4 = (const float4*)(qp + base + g * 16);
    const float4* k4 = (const float4*)(kp + base + g * 16);
#pragma unroll
    for (int ci = 0; ci < 4; ++ci) {
      float4 a = q4[ci];
      S.q[4 * ci + 0] = a.x; S.q[4 * ci + 1] = a.y;
      S.q[4 * ci + 2] = a.z; S.q[4 * ci + 3] = a.w;
      float4 bb = k4[ci];
      S.k[4 * ci + 0] = bb.x; S.k[4 * ci + 1] = bb.y;
      S.k[4 * ci + 2] = bb.z; S.k[4 * ci + 3] = bb.w;
    }
    S.fr = fpg[base + irow];
    S.ir = ipg[base + irow];
    S.vr = vp[base + irow];
    S.og = opg[base + irow];
    S.qn0 = qp[base + lane];   S.qn1 = qp[base + 64 + lane];
    S.kn0 = kp[base + lane];   S.kn1 = kp[base + 64 + lane];
    S.fn0 = fpg[base + lane];  S.fn1 = fpg[base + 64 + lane];
    S.gn0 = ipg[base + lane];  S.gn1 = ipg[base + 64 + lane];
  };

  auto compute = [&](int t, const Step& S) {
    // denom from OLD n (reference uses carry n, not n_new)
    float dp = n0 * S.qn0 + n1 * S.qn1;
#pragma unroll
    for (int m = 1; m < 64; m <<= 1) dp += __shfl_xor(dp, m, 64);
    const float inv = 1.0f / fmaxf(fabsf(dp), 1.0f);

    // h_tilde from OLD C; reduce across the 8 column-groups (same row lanes)
    float acc = 0.f;
#pragma unroll
    for (int c = 0; c < 16; ++c) acc = fmaf(C[c], S.q[c], acc);
    acc += __shfl_xor(acc, 8, 64);
    acc += __shfl_xor(acc, 16, 64);
    acc += __shfl_xor(acc, 32, 64);
    if (g == 0)
      hout[(size_t)(b * TT + t) * HH + irow] = S.og * acc * inv;

    // n update
    n0 = fmaf(S.fn0, n0, S.gn0 * S.kn0);
    n1 = fmaf(S.fn1, n1, S.gn1 * S.kn1);

    // C update: C = f[i]*C + (i[i]*v[i])*k[j]
    const float ar = S.ir * S.vr;
#pragma unroll
    for (int c = 0; c < 16; ++c) C[c] = fmaf(S.fr, C[c], ar * S.k[c]);
  };

  Step s0, s1;
  load_step(0, s0);
#pragma unroll 1
  for (int t = 0; t < TT; t += 2) {
    load_step(t + 1, s1);
    compute(t, s0);
    if (t + 2 < TT) load_step(t + 2, s0);
    compute(t + 1, s1);
  }
}

// ---------------------------------------------------------------------------
extern "C" void kernel_launch(void* const* d_in, const int* in_sizes, int n_in,
                              void* d_out, int out_size, void* d_ws,
                              size_t ws_size, hipStream_t stream) {
  (void)in_sizes; (void)n_in; (void)out_size; (void)ws_size;
  const float* x = (const float*)d_in[0];
  float* act = (float*)d_ws;            // 6 * BTH floats
  float* hbuf = act + 6 * BTH;          // BTH floats (layer-1 output)

  for (int l = 0; l < 2; ++l) {
    ProjArgs pa;
    for (int j = 0; j < 6; ++j) {
      pa.W[j] = (const float*)d_in[1 + j] + (size_t)l * HH * DD;
      pa.b[j] = (const float*)d_in[7 + j] + (size_t)l * HH;
    }
    const float* xin = (l == 0) ? x : hbuf;
    float* hdst = (l == 0) ? hbuf : (float*)d_out;
    proj_kernel<<<dim3(BT_ / NROW, 6), 256, 0, stream>>>(xin, pa, act);
    scan_kernel<<<128, 64, 0, stream>>>(act, hdst);
  }
}

// Round 3
// 644.117 us; speedup vs baseline: 1.1838x; 1.1838x over previous
//
#include <hip/hip_runtime.h>
#include <math.h>

// Problem constants (B, T, D, H, L) = (8, 512, 128, 128, 2). All fp32 I/O.
#define BB 8
#define TT 512
#define DD 128
#define HH 128
#define BT_ (BB * TT)                 // 4096
#define NROW2 16                      // rows of X per projection block
static const size_t BTH = (size_t)BT_ * HH;  // 524288

struct ProjArgs {
  const float* W[6];  // each already offset to current layer, (H, D)
  const float* b[6];  // each already offset to current layer, (H)
};

// DPP-based partial-sum add: x += dpp_shifted(x), invalid lanes contribute 0.
template <int CTRL>
__device__ __forceinline__ float dpp_add(float x) {
  int y = __builtin_amdgcn_update_dpp(0, __builtin_bit_cast(int, x), CTRL,
                                      0xF, 0xF, true);
  return x + __builtin_bit_cast(float, y);
}

// ---------------------------------------------------------------------------
// Projection kernel: act[p][row][h] = act_p( sum_d X[row][d] * W_p[h][d] + b_p[h] )
// p: 0=q 1=k(*1/sqrt(H)) 2=v 3=i(exp) 4=f(sigmoid) 5=o(sigmoid)
// grid: (BT_/NROW2, 6), block 256. Thread = 4 h  x 2 rows (8 accumulators):
// per d-quad: 4 global b128 (W) + 2 LDS b128 (x) + 32 fma  -> VALU-bound.
// ---------------------------------------------------------------------------
__global__ __launch_bounds__(256)
void proj_kernel(const float* __restrict__ X, ProjArgs args,
                 float* __restrict__ act) {
  __shared__ float4 xs4[NROW2 * 32];  // 16 rows x 128 floats
  const int p = blockIdx.y;
  const int row0 = blockIdx.x * NROW2;
  const int tid = threadIdx.x;
  {
    const float4* xg = (const float4*)(X + (size_t)row0 * DD);
    xs4[tid] = xg[tid];
    xs4[tid + 256] = xg[tid + 256];
  }
  __syncthreads();

  const int hg = (tid & 31) * 4;   // h = hg..hg+3
  const int rg = (tid >> 5) * 2;   // rows rg, rg+1
  const float* Wp = args.W[p];
  const float4* w0 = (const float4*)(Wp + (size_t)(hg + 0) * DD);
  const float4* w1 = (const float4*)(Wp + (size_t)(hg + 1) * DD);
  const float4* w2 = (const float4*)(Wp + (size_t)(hg + 2) * DD);
  const float4* w3 = (const float4*)(Wp + (size_t)(hg + 3) * DD);
  const float4* x0p = &xs4[rg * 32];
  const float4* x1p = &xs4[(rg + 1) * 32];

  float a00 = 0.f, a01 = 0.f, a02 = 0.f, a03 = 0.f;
  float a10 = 0.f, a11 = 0.f, a12 = 0.f, a13 = 0.f;
#pragma unroll 8
  for (int qq = 0; qq < 32; ++qq) {
    const float4 wa = w0[qq], wb = w1[qq], wc = w2[qq], wd = w3[qq];
    const float4 x0 = x0p[qq], x1 = x1p[qq];
    a00 = fmaf(x0.x, wa.x, fmaf(x0.y, wa.y, fmaf(x0.z, wa.z, fmaf(x0.w, wa.w, a00))));
    a01 = fmaf(x0.x, wb.x, fmaf(x0.y, wb.y, fmaf(x0.z, wb.z, fmaf(x0.w, wb.w, a01))));
    a02 = fmaf(x0.x, wc.x, fmaf(x0.y, wc.y, fmaf(x0.z, wc.z, fmaf(x0.w, wc.w, a02))));
    a03 = fmaf(x0.x, wd.x, fmaf(x0.y, wd.y, fmaf(x0.z, wd.z, fmaf(x0.w, wd.w, a03))));
    a10 = fmaf(x1.x, wa.x, fmaf(x1.y, wa.y, fmaf(x1.z, wa.z, fmaf(x1.w, wa.w, a10))));
    a11 = fmaf(x1.x, wb.x, fmaf(x1.y, wb.y, fmaf(x1.z, wb.z, fmaf(x1.w, wb.w, a11))));
    a12 = fmaf(x1.x, wc.x, fmaf(x1.y, wc.y, fmaf(x1.z, wc.z, fmaf(x1.w, wc.w, a12))));
    a13 = fmaf(x1.x, wd.x, fmaf(x1.y, wd.y, fmaf(x1.z, wd.z, fmaf(x1.w, wd.w, a13))));
  }

  const float4 bv = *(const float4*)(args.b[p] + hg);
  float r0[4] = {a00 + bv.x, a01 + bv.y, a02 + bv.z, a03 + bv.w};
  float r1[4] = {a10 + bv.x, a11 + bv.y, a12 + bv.z, a13 + bv.w};
#pragma unroll
  for (int j = 0; j < 4; ++j) {
    if (p == 1) { r0[j] *= 0.088388347648318447f; r1[j] *= 0.088388347648318447f; }
    else if (p == 3) { r0[j] = __expf(r0[j]); r1[j] = __expf(r1[j]); }
    else if (p >= 4) {
      r0[j] = 1.0f / (1.0f + __expf(-r0[j]));
      r1[j] = 1.0f / (1.0f + __expf(-r1[j]));
    }
  }
  float* dst = act + (size_t)p * BTH + (size_t)(row0 + rg) * HH + hg;
  *(float4*)dst = make_float4(r0[0], r0[1], r0[2], r0[3]);
  *(float4*)(dst + HH) = make_float4(r1[0], r1[1], r1[2], r1[3]);
}

// ---------------------------------------------------------------------------
// Scan kernel: sequential over T. One wave per block; 256 blocks = 1/CU.
// Block = (batch b, 4-row slice of C). Lane: r = lane>>4 (row sl*4+r),
// g = lane&15 (cols g*8..g*8+8, 8 C elements in registers).
// n (length-128) owned as n[2*lane], n[2*lane+1] (float2 loads), redundant
// per block. Reductions via DPP (VALU latency, no LDS pipe):
//   denom: 6 rounds -> lane 63 -> readlane -> SGPR broadcast
//   C.q row sum over 16 lanes: 4 rounds -> lane 16r+15 stores h.
// h_t uses OLD C and OLD n (per reference), then states update.
// ---------------------------------------------------------------------------
struct Step {
  float q[8], k[8];
  float fr, ir, vr, og;      // row scalars at irow
  float2 qn, kn, fn, gn;     // n-lane values at 2*lane, 2*lane+1
};

__global__ __launch_bounds__(64)
void scan_kernel(const float* __restrict__ act, float* __restrict__ hout) {
  const int lane = threadIdx.x;
  const int b = blockIdx.x >> 5;   // 32 slices per batch
  const int sl = blockIdx.x & 31;
  const int r = lane >> 4;
  const int g = lane & 15;
  const int irow = sl * 4 + r;
  const size_t boff = (size_t)b * TT * HH;
  const float* qp  = act + boff;
  const float* kp  = act + BTH + boff;
  const float* vp  = act + 2 * BTH + boff;
  const float* ipg = act + 3 * BTH + boff;
  const float* fpg = act + 4 * BTH + boff;
  const float* opg = act + 5 * BTH + boff;

  float C[8];
#pragma unroll
  for (int c = 0; c < 8; ++c) C[c] = 0.f;
  float nx = 0.f, ny = 0.f;

  auto load_step = [&](int t, Step& S) {
    const int base = t * HH;
    const float4 q0 = *(const float4*)(qp + base + g * 8);
    const float4 q1 = *(const float4*)(qp + base + g * 8 + 4);
    const float4 k0 = *(const float4*)(kp + base + g * 8);
    const float4 k1 = *(const float4*)(kp + base + g * 8 + 4);
    S.q[0] = q0.x; S.q[1] = q0.y; S.q[2] = q0.z; S.q[3] = q0.w;
    S.q[4] = q1.x; S.q[5] = q1.y; S.q[6] = q1.z; S.q[7] = q1.w;
    S.k[0] = k0.x; S.k[1] = k0.y; S.k[2] = k0.z; S.k[3] = k0.w;
    S.k[4] = k1.x; S.k[5] = k1.y; S.k[6] = k1.z; S.k[7] = k1.w;
    S.fr = fpg[base + irow];
    S.ir = ipg[base + irow];
    S.vr = vp[base + irow];
    S.og = opg[base + irow];
    S.qn = *(const float2*)(qp + base + 2 * lane);
    S.kn = *(const float2*)(kp + base + 2 * lane);
    S.fn = *(const float2*)(fpg + base + 2 * lane);
    S.gn = *(const float2*)(ipg + base + 2 * lane);
  };

  auto compute = [&](int t, const Step& S) {
    // denom from OLD n: full 64-lane DPP sum -> lane 63 -> SGPR
    float dp = fmaf(nx, S.qn.x, ny * S.qn.y);
    dp = dpp_add<0x111>(dp);  // row_shr:1
    dp = dpp_add<0x112>(dp);  // row_shr:2
    dp = dpp_add<0x114>(dp);  // row_shr:4
    dp = dpp_add<0x118>(dp);  // row_shr:8
    dp = dpp_add<0x142>(dp);  // row_bcast:15
    dp = dpp_add<0x143>(dp);  // row_bcast:31
    const float dpv = __builtin_bit_cast(
        float, __builtin_amdgcn_readlane(__builtin_bit_cast(int, dp), 63));
    const float inv = __builtin_amdgcn_rcpf(fmaxf(fabsf(dpv), 1.0f));

    // h_tilde from OLD C: row sum over 16 col-group lanes -> lane 16r+15
    float acc = 0.f;
#pragma unroll
    for (int c = 0; c < 8; ++c) acc = fmaf(C[c], S.q[c], acc);
    acc = dpp_add<0x111>(acc);
    acc = dpp_add<0x112>(acc);
    acc = dpp_add<0x114>(acc);
    acc = dpp_add<0x118>(acc);
    if (g == 15)
      hout[(size_t)(b * TT + t) * HH + irow] = S.og * acc * inv;

    // n update
    nx = fmaf(S.fn.x, nx, S.gn.x * S.kn.x);
    ny = fmaf(S.fn.y, ny, S.gn.y * S.kn.y);

    // C update: C = f[i]*C + (i[i]*v[i])*k[j]
    const float ar = S.ir * S.vr;
#pragma unroll
    for (int c = 0; c < 8; ++c) C[c] = fmaf(S.fr, C[c], ar * S.k[c]);
  };

  Step s0, s1;
  load_step(0, s0);
#pragma unroll 1
  for (int t = 0; t < TT; t += 2) {
    load_step(t + 1, s1);
    compute(t, s0);
    if (t + 2 < TT) load_step(t + 2, s0);
    compute(t + 1, s1);
  }
}

// ---------------------------------------------------------------------------
extern "C" void kernel_launch(void* const* d_in, const int* in_sizes, int n_in,
                              void* d_out, int out_size, void* d_ws,
                              size_t ws_size, hipStream_t stream) {
  (void)in_sizes; (void)n_in; (void)out_size; (void)ws_size;
  const float* x = (const float*)d_in[0];
  float* act = (float*)d_ws;            // 6 * BTH floats
  float* hbuf = act + 6 * BTH;          // BTH floats (layer-1 output)

  for (int l = 0; l < 2; ++l) {
    ProjArgs pa;
    for (int j = 0; j < 6; ++j) {
      pa.W[j] = (const float*)d_in[1 + j] + (size_t)l * HH * DD;
      pa.b[j] = (const float*)d_in[7 + j] + (size_t)l * HH;
    }
    const float* xin = (l == 0) ? x : hbuf;
    float* hdst = (l == 0) ? hbuf : (float*)d_out;
    proj_kernel<<<dim3(BT_ / NROW2, 6), 256, 0, stream>>>(xin, pa, act);
    scan_kernel<<<256, 64, 0, stream>>>(act, hdst);
  }
}

// Round 4
// 324.705 us; speedup vs baseline: 2.3484x; 1.9837x over previous
//
#include <hip/hip_runtime.h>
#include <math.h>

// (B, T, D, H, L) = (8, 512, 128, 128, 2). All fp32 I/O.
#define BB 8
#define TT 512
#define DD 128
#define HH 128
#define BT_ (BB * TT)                 // 4096
static const size_t BTH = (size_t)BT_ * HH;  // 524288

// ws layout: act planes [0,6*BTH) : q | k | ifpack(2*BTH) | vopack(2*BTH)
//   q:      act + 0      [row][h]
//   k:      act + BTH    [row][h]
//   ifpack: act + 2*BTH  [row][2h+{0:i,1:f}]
//   vopack: act + 4*BTH  [row][2h+{0:v,1:o}]
// hbuf = act + 6*BTH (layer-1 output, planar [row][h])
// Wt (12 x 128 x 128 transposed weights) lives in d_out's first 196608
// floats; consumed by both proj dispatches, then fully overwritten by the
// final scan (stream-ordered, so this is safe).

struct WArgs { const float* W[6]; };
struct BArgs { const float* b[6]; };

template <int CTRL>
__device__ __forceinline__ float dpp_add(float x) {
  int y = __builtin_amdgcn_update_dpp(0, __builtin_bit_cast(int, x), CTRL,
                                      0xF, 0xF, true);
  return x + __builtin_bit_cast(float, y);
}

// ---------------------------------------------------------------------------
// Transpose all 12 weight slabs: Wt[l*6+p][d][h] = W_p[l][h][d].
// grid (16, 12): 4x4 tiles of 32x32 per slab. block 256.
// ---------------------------------------------------------------------------
__global__ __launch_bounds__(256)
void transpose_w(WArgs w, float* __restrict__ Wt) {
  __shared__ float t[32][33];
  const int l = blockIdx.y / 6, p = blockIdx.y % 6;
  const float* src = w.W[p] + (size_t)l * HH * DD;
  float* dst = Wt + (size_t)blockIdx.y * HH * DD;
  const int ty0 = (blockIdx.x >> 2) * 32, tx0 = (blockIdx.x & 3) * 32;
  const int tx = threadIdx.x & 31, ty = threadIdx.x >> 5;
#pragma unroll
  for (int j = 0; j < 32; j += 8)
    t[ty + j][tx] = src[(size_t)(ty0 + ty + j) * DD + tx0 + tx];
  __syncthreads();
#pragma unroll
  for (int j = 0; j < 32; j += 8)
    dst[(size_t)(tx0 + ty + j) * HH + ty0 + tx] = t[tx][ty + j];
}

// ---------------------------------------------------------------------------
// Projection: out[p][row][h] = act_p( sum_d X[row][d] * Wt_p[d][h] + b_p[h] )
// Rank-1-update GEMM, coalesced Wt rows. grid (BT_/32, 6), block 256.
// Thread = 2 rows x 8 h. LDS X tile padded to 132 (bank-conflict-free).
// ---------------------------------------------------------------------------
__global__ __launch_bounds__(256)
void proj_kernel(const float* __restrict__ X, const float* __restrict__ Wtl,
                 BArgs args, float* __restrict__ act) {
  __shared__ float xs[32][132];
  const int p = blockIdx.y;
  const int row0 = blockIdx.x * 32;
  const int tid = threadIdx.x;
  {
    const float4* xg = (const float4*)(X + (size_t)row0 * DD);
#pragma unroll
    for (int i = 0; i < 4; ++i) {
      int u = tid + 256 * i;  // float4 index within 32x128 tile
      float4 v = xg[u];
      *(float4*)&xs[u >> 5][(u & 31) * 4] = v;
    }
  }
  __syncthreads();

  const int h0 = (tid & 15) * 8;
  const int r0 = (tid >> 4) * 2;
  const float* wtp = Wtl + (size_t)p * HH * DD;

  float acc[2][8];
#pragma unroll
  for (int r = 0; r < 2; ++r)
#pragma unroll
    for (int j = 0; j < 8; ++j) acc[r][j] = 0.f;

  for (int d0 = 0; d0 < DD; d0 += 4) {
    float4 wa[4], wb[4];
#pragma unroll
    for (int i = 0; i < 4; ++i) {
      wa[i] = *(const float4*)(wtp + (size_t)(d0 + i) * HH + h0);
      wb[i] = *(const float4*)(wtp + (size_t)(d0 + i) * HH + h0 + 4);
    }
    float4 x0 = *(const float4*)&xs[r0][d0];
    float4 x1 = *(const float4*)&xs[r0 + 1][d0];
    const float xa[4] = {x0.x, x0.y, x0.z, x0.w};
    const float xb[4] = {x1.x, x1.y, x1.z, x1.w};
#pragma unroll
    for (int i = 0; i < 4; ++i) {
      acc[0][0] = fmaf(xa[i], wa[i].x, acc[0][0]);
      acc[0][1] = fmaf(xa[i], wa[i].y, acc[0][1]);
      acc[0][2] = fmaf(xa[i], wa[i].z, acc[0][2]);
      acc[0][3] = fmaf(xa[i], wa[i].w, acc[0][3]);
      acc[0][4] = fmaf(xa[i], wb[i].x, acc[0][4]);
      acc[0][5] = fmaf(xa[i], wb[i].y, acc[0][5]);
      acc[0][6] = fmaf(xa[i], wb[i].z, acc[0][6]);
      acc[0][7] = fmaf(xa[i], wb[i].w, acc[0][7]);
      acc[1][0] = fmaf(xb[i], wa[i].x, acc[1][0]);
      acc[1][1] = fmaf(xb[i], wa[i].y, acc[1][1]);
      acc[1][2] = fmaf(xb[i], wa[i].z, acc[1][2]);
      acc[1][3] = fmaf(xb[i], wa[i].w, acc[1][3]);
      acc[1][4] = fmaf(xb[i], wb[i].x, acc[1][4]);
      acc[1][5] = fmaf(xb[i], wb[i].y, acc[1][5]);
      acc[1][6] = fmaf(xb[i], wb[i].z, acc[1][6]);
      acc[1][7] = fmaf(xb[i], wb[i].w, acc[1][7]);
    }
  }

  const float4 b0 = *(const float4*)(args.b[p] + h0);
  const float4 b1 = *(const float4*)(args.b[p] + h0 + 4);
  const float bias[8] = {b0.x, b0.y, b0.z, b0.w, b1.x, b1.y, b1.z, b1.w};
#pragma unroll
  for (int r = 0; r < 2; ++r) {
    const size_t row = (size_t)row0 + r0 + r;
    float v[8];
#pragma unroll
    for (int j = 0; j < 8; ++j) {
      float a = acc[r][j] + bias[j];
      if (p == 1)      a *= 0.088388347648318447f;   // 1/sqrt(128)
      else if (p == 3) a = __expf(a);
      else if (p >= 4) a = 1.0f / (1.0f + __expf(-a));
      v[j] = a;
    }
    if (p == 0) {
      float* dst = act + row * HH + h0;
      *(float4*)dst = make_float4(v[0], v[1], v[2], v[3]);
      *(float4*)(dst + 4) = make_float4(v[4], v[5], v[6], v[7]);
    } else if (p == 1) {
      float* dst = act + BTH + row * HH + h0;
      *(float4*)dst = make_float4(v[0], v[1], v[2], v[3]);
      *(float4*)(dst + 4) = make_float4(v[4], v[5], v[6], v[7]);
    } else if (p == 3 || p == 4) {       // i -> slot 0, f -> slot 1
      float* dst = act + 2 * BTH + row * 2 * HH + 2 * h0 + (p == 3 ? 0 : 1);
#pragma unroll
      for (int j = 0; j < 8; ++j) dst[2 * j] = v[j];
    } else {                             // v -> slot 0, o -> slot 1
      float* dst = act + 4 * BTH + row * 2 * HH + 2 * h0 + (p == 2 ? 0 : 1);
#pragma unroll
      for (int j = 0; j < 8; ++j) dst[2 * j] = v[j];
    }
  }
}

// ---------------------------------------------------------------------------
// Scan: sequential over T, depth-4 register prefetch. 256 single-wave blocks.
// b = blockIdx&7 (XCD co-location: one batch's planes -> one XCD's L2).
// Lane: r = lane>>4 -> row sl*4+r; g = lane&15 -> cols 8g..8g+8 (C[8]).
// n owned as n[2*lane], n[2*lane+1]. h uses OLD C, OLD n (per reference).
// ---------------------------------------------------------------------------
struct Step {
  float q[8], k[8];
  float2 qn, kn;   // q,k at 2*lane
  float4 ifn;      // i[2l], f[2l], i[2l+1], f[2l+1]
  float2 ifr;      // i[irow], f[irow]
  float2 vor;      // v[irow], o[irow]
};

__global__ __launch_bounds__(64)
void scan_kernel(const float* __restrict__ act, float* __restrict__ hout) {
  const int lane = threadIdx.x;
  const int b = blockIdx.x & 7;
  const int sl = blockIdx.x >> 3;
  const int r = lane >> 4;
  const int g = lane & 15;
  const int irow = sl * 4 + r;
  const size_t boff = (size_t)b * TT * HH;
  const float* qp = act + boff;
  const float* kp = act + BTH + boff;
  const float* ifp = act + 2 * BTH + 2 * boff;
  const float* vop = act + 4 * BTH + 2 * boff;

  float C[8];
#pragma unroll
  for (int c = 0; c < 8; ++c) C[c] = 0.f;
  float nx = 0.f, ny = 0.f;

  auto load_step = [&](int t, Step& S) {
    const int base = t * HH, base2 = t * 2 * HH;
    float4 q0 = *(const float4*)(qp + base + g * 8);
    float4 q1 = *(const float4*)(qp + base + g * 8 + 4);
    float4 k0 = *(const float4*)(kp + base + g * 8);
    float4 k1 = *(const float4*)(kp + base + g * 8 + 4);
    S.q[0] = q0.x; S.q[1] = q0.y; S.q[2] = q0.z; S.q[3] = q0.w;
    S.q[4] = q1.x; S.q[5] = q1.y; S.q[6] = q1.z; S.q[7] = q1.w;
    S.k[0] = k0.x; S.k[1] = k0.y; S.k[2] = k0.z; S.k[3] = k0.w;
    S.k[4] = k1.x; S.k[5] = k1.y; S.k[6] = k1.z; S.k[7] = k1.w;
    S.qn = *(const float2*)(qp + base + 2 * lane);
    S.kn = *(const float2*)(kp + base + 2 * lane);
    S.ifn = *(const float4*)(ifp + base2 + 4 * lane);
    S.ifr = *(const float2*)(ifp + base2 + 2 * irow);
    S.vor = *(const float2*)(vop + base2 + 2 * irow);
  };

  auto compute = [&](int t, const Step& S) {
    // denom from OLD n: 64-lane DPP sum -> lane 63 -> SGPR broadcast
    float dp = fmaf(nx, S.qn.x, ny * S.qn.y);
    dp = dpp_add<0x111>(dp);  // row_shr:1
    dp = dpp_add<0x112>(dp);  // row_shr:2
    dp = dpp_add<0x114>(dp);  // row_shr:4
    dp = dpp_add<0x118>(dp);  // row_shr:8
    dp = dpp_add<0x142>(dp);  // row_bcast:15
    dp = dpp_add<0x143>(dp);  // row_bcast:31
    const float dpv = __builtin_bit_cast(
        float, __builtin_amdgcn_readlane(__builtin_bit_cast(int, dp), 63));
    const float inv = __builtin_amdgcn_rcpf(fmaxf(fabsf(dpv), 1.0f));

    // h_tilde from OLD C: sum over 16 col-lanes -> lane g==15
    float acc = 0.f;
#pragma unroll
    for (int c = 0; c < 8; ++c) acc = fmaf(C[c], S.q[c], acc);
    acc = dpp_add<0x111>(acc);
    acc = dpp_add<0x112>(acc);
    acc = dpp_add<0x114>(acc);
    acc = dpp_add<0x118>(acc);
    if (g == 15)
      hout[((size_t)b * TT + t) * HH + irow] = S.vor.y * acc * inv;

    // n update
    nx = fmaf(S.ifn.y, nx, S.ifn.x * S.kn.x);
    ny = fmaf(S.ifn.w, ny, S.ifn.z * S.kn.y);

    // C update: C = f[row]*C + (i[row]*v[row])*k[col]
    const float ar = S.ifr.x * S.vor.x;
#pragma unroll
    for (int c = 0; c < 8; ++c) C[c] = fmaf(S.ifr.y, C[c], ar * S.k[c]);
  };

  Step S0, S1, S2, S3;
  load_step(0, S0); load_step(1, S1); load_step(2, S2); load_step(3, S3);
#pragma unroll 1
  for (int t = 0; t < TT; t += 4) {
    // prefetch t+4..t+7; tail over-reads stay inside ws (harmless, unused)
    compute(t + 0, S0); load_step(t + 4, S0);
    compute(t + 1, S1); load_step(t + 5, S1);
    compute(t + 2, S2); load_step(t + 6, S2);
    compute(t + 3, S3); load_step(t + 7, S3);
  }
}

// ---------------------------------------------------------------------------
extern "C" void kernel_launch(void* const* d_in, const int* in_sizes, int n_in,
                              void* d_out, int out_size, void* d_ws,
                              size_t ws_size, hipStream_t stream) {
  (void)in_sizes; (void)n_in; (void)out_size; (void)ws_size;
  const float* x = (const float*)d_in[0];
  float* act = (float*)d_ws;            // 6 * BTH floats
  float* hbuf = act + 6 * BTH;          // BTH floats
  float* Wt = (float*)d_out;            // 12*128*128 floats, overwritten later

  WArgs wa;
  for (int j = 0; j < 6; ++j) wa.W[j] = (const float*)d_in[1 + j];
  transpose_w<<<dim3(16, 12), 256, 0, stream>>>(wa, Wt);

  for (int l = 0; l < 2; ++l) {
    BArgs ba;
    for (int j = 0; j < 6; ++j)
      ba.b[j] = (const float*)d_in[7 + j] + (size_t)l * HH;
    const float* wtl = Wt + (size_t)l * 6 * HH * DD;
    const float* xin = (l == 0) ? x : hbuf;
    float* hdst = (l == 0) ? hbuf : (float*)d_out;
    proj_kernel<<<dim3(BT_ / 32, 6), 256, 0, stream>>>(xin, wtl, ba, act);
    scan_kernel<<<256, 64, 0, stream>>>(act, hdst);
  }
}